// Round 9
// baseline (148.736 us; speedup 1.0000x reference)
//
#include <hip/hip_runtime.h>

typedef short bf16x8 __attribute__((ext_vector_type(8)));
typedef float f32x4 __attribute__((ext_vector_type(4)));
typedef unsigned short u16;

#define NNODE 196608
#define FF 32
#define COLS 256   // UP * OUT_FEATURES
#define KTOT 288   // KK * FF
#define WELEMS (COLS * KTOT)   // 73728 elems = 144 KB bf16
#define TPB 6                  // tiles per block (1536 / 256)

__device__ __forceinline__ u16 f2bf(float f) {
    unsigned u = __builtin_bit_cast(unsigned, f);
    return (u16)((u + 0x7fffu + ((u >> 16) & 1u)) >> 16);  // RTNE
}

// prep 1: x (2,N,32) f32 -> xb2 bf16 INTERLEAVED: xb2[node][0:32]=t0 feats,
// xb2[node][32:64]=t1 feats -> one 128-B line per node (gather = 1 line).
__global__ void cvt_x(const float* __restrict__ x, u16* __restrict__ xb2, int n8) {
    int i = blockIdx.x * blockDim.x + threadIdx.x;
    if (i >= n8) return;
    int og   = i * 8;           // output element index (u16 units)
    int node = og >> 6;
    int rem  = og & 63;
    int s    = rem >> 5;        // t-slice
    int f0   = rem & 31;        // feature start (0,8,16,24)
    const float* src = x + ((size_t)s * NNODE + node) * FF + f0;
    f32x4 v0 = *(const f32x4*)src;
    f32x4 v1 = *(const f32x4*)(src + 4);
    union { u16 h[8]; bf16x8 v; } r;
    #pragma unroll
    for (int j = 0; j < 4; ++j) r.h[j] = f2bf(v0[j]);
    #pragma unroll
    for (int j = 0; j < 4; ++j) r.h[4 + j] = f2bf(v1[j]);
    *((bf16x8*)xb2 + i) = r.v;
}

// prep 2: W (K,F,UP,O) f32 -> Wt bf16, MFMA fragment-linear:
// Wt[f*512 + lane*8 + e] = W[kf][c], f = kk*16+ct, c = ct*16+(lane&15),
// kf = kk*32 + (lane>>4)*8 + e. Wave ds_read_b128 of a frag: lane-linear.
__global__ void cvt_w(const float* __restrict__ W, u16* __restrict__ Wt) {
    int gid = blockIdx.x * 256 + threadIdx.x;   // 73728 total
    int f      = gid >> 9;
    int within = gid & 511;
    int lane   = within >> 3;
    int e      = within & 7;
    int kk = f >> 4, ct = f & 15;
    int cl = lane & 15, q = lane >> 4;
    int c  = ct * 16 + cl;
    int kf = kk * 32 + q * 8 + e;
    Wt[gid] = f2bf(W[(size_t)kf * COLS + c]);
}

// main: grid 256 (1 blk/CU via 145 KB LDS), 1024 thr = 16 waves (4/SIMD —
// 2x the 8-wave R8 occupancy), static 6 tiles/blk.
// Wave w: node-group g = w>>1 (16 nodes), t-slice s = w&1. The paired waves
// (2g, 2g+1) gather halves of the SAME 128-B xb2 line (L2-merged), so
// beyond-L2 traffic stays C=1. acc = 16 f32x4 = 64 VGPR -> fits 128 cap.
// Operand-swapped MFMA (A = W-frag from LDS, B = x-frag gathered): lane
// owns out[s][node][ct*16+q*4..+3] -> 16 f32x4 stores/lane/tile.
// R6/R7 lesson kept: NO live state across the tile seam (spill hazard).
__global__ __launch_bounds__(1024, 4) void updown_main(
    const u16* __restrict__ xb2, const u16* __restrict__ Wt,
    const int* __restrict__ adjc, const float* __restrict__ bias,
    float* __restrict__ out)
{
    __shared__ __align__(16) u16 wlds[WELEMS];   // 144 KB, read-only after load
    __shared__ __align__(16) float blds[COLS];   // 1 KB bias

    const int tid = threadIdx.x;

    #pragma unroll
    for (int i = 0; i < 9; ++i)
        *(bf16x8*)(wlds + i * 8192 + tid * 8) =
            *(const bf16x8*)(Wt + i * 8192 + tid * 8);
    if (tid < 64) ((f32x4*)blds)[tid] = ((const f32x4*)bias)[tid];
    __syncthreads();   // the only full barrier

    const int w    = tid >> 6;
    const int lane = tid & 63;
    const int l15  = lane & 15;
    const int q    = lane >> 4;
    const int g    = w >> 1;            // node-group 0..7
    const int s    = w & 1;             // t-slice
    const u16* wbase = wlds + lane * 8;        // + kk*8192 + ct*512
    const float* bb  = blds + q * 4;           // + ct*16
    const u16* xbs   = xb2 + s * 32;           // slice offset within node line

    const int node0 = blockIdx.x * (TPB * 128) + g * 16 + l15;

    for (int tt = 0; tt < TPB; ++tt) {
        const int node  = node0 + tt * 128;
        const int* arow = adjc + (size_t)node * 9;

        // tile prologue: 2 gathers in flight + idx for the third
        int i0 = arow[0];
        int i1 = arow[1];
        bf16x8 aC = *(const bf16x8*)(xbs + (size_t)i0 * 64 + q * 8);
        bf16x8 aN = *(const bf16x8*)(xbs + (size_t)i1 * 64 + q * 8);
        int idxP = arow[2];   // idx one iteration ahead of its gather

        // acc init = bias (lgkm counter — doesn't touch the vmcnt FIFO)
        f32x4 acc[16];
        #pragma unroll
        for (int ct = 0; ct < 16; ++ct)
            acc[ct] = *(const f32x4*)(bb + ct * 16);

        #pragma unroll
        for (int kk = 0; kk < 9; ++kk) {
            bf16x8 aNN;
            if (kk < 7)   // gather kk+2 using idx loaded last iteration
                aNN = *(const bf16x8*)(xbs + (size_t)idxP * 64 + q * 8);
            if (kk < 6) idxP = arow[kk + 3];

            const u16* wk = wbase + kk * 8192;
            #pragma unroll
            for (int ct = 0; ct < 16; ++ct) {
                bf16x8 af = *(const bf16x8*)(wk + ct * 512);
                acc[ct] = __builtin_amdgcn_mfma_f32_16x16x32_bf16(af, aC, acc[ct], 0, 0, 0);
            }
            if (kk < 8) aC = aN;
            if (kk < 7) aN = aNN;
        }

        // stores: lane-contiguous f32x4, dense full-line coverage
        float* o = out + ((size_t)s * NNODE + node) * COLS + q * 4;
        #pragma unroll
        for (int ct = 0; ct < 16; ++ct)
            *(f32x4*)(o + ct * 16) = acc[ct];

        // phase-lock the 16 waves (L2 gather-line sharing); raw barrier:
        // NO vmcnt drain — stores stay in flight under next tile's compute
        __builtin_amdgcn_s_barrier();
    }
}

extern "C" void kernel_launch(void* const* d_in, const int* in_sizes, int n_in,
                              void* d_out, int out_size, void* d_ws, size_t ws_size,
                              hipStream_t stream) {
    const float* x    = (const float*)d_in[0];
    const int*   adjc = (const int*)d_in[1];
    const float* W    = (const float*)d_in[2];
    const float* b    = (const float*)d_in[3];
    float* out = (float*)d_out;

    u16* xb2 = (u16*)d_ws;                           // 196608*64 bf16 = 25.2 MB
    u16* Wt  = xb2 + (size_t)NNODE * 64;             // 73728 bf16 = 144 KB

    cvt_x<<<dim3(6144), dim3(256), 0, stream>>>(x, xb2, 1572864);
    cvt_w<<<dim3(288), dim3(256), 0, stream>>>(W, Wt);
    updown_main<<<dim3(256), dim3(1024), 0, stream>>>(xb2, Wt, adjc, b, out);
}